// Round 4
// baseline (1658.532 us; speedup 1.0000x reference)
//
#include <hip/hip_runtime.h>
#include <cstdint>
#include <cstddef>

#define TOPK 50
#define B_ROWS 8192
#define IN_DIM 1024
#define HID_DIM 16384
#define TKT 512   // topk threads
#define CAND_CAP 1024

typedef unsigned short u16;
typedef __attribute__((ext_vector_type(8))) short bf16x8;
typedef __attribute__((ext_vector_type(4))) float f32x4;

// ---------- helpers ----------
__device__ inline u16 f2bf_rne(float f) {
  unsigned u = __float_as_uint(f);
  unsigned r = 0x7FFFu + ((u >> 16) & 1u);
  return (u16)((u + r) >> 16);
}
__device__ inline float bf2f(u16 h) { return __uint_as_float(((unsigned)h) << 16); }
__device__ inline float ninf() { return __uint_as_float(0xFF800000u); }

__device__ inline void gload16(const void* g, void* l) {
  __builtin_amdgcn_global_load_lds(
      (const __attribute__((address_space(1))) void*)g,
      (__attribute__((address_space(3))) void*)l, 16, 0, 0);
}

// ---------- split f32 -> bf16 h/m/l ----------
__global__ __launch_bounds__(256)
void split3_kernel(const float* __restrict__ in, u16* __restrict__ h,
                   u16* __restrict__ m, u16* __restrict__ l, int n4) {
  int i = blockIdx.x * 256 + threadIdx.x;
  const int stride = gridDim.x * 256;
  for (; i < n4; i += stride) {
    const float4 f = reinterpret_cast<const float4*>(in)[i];
    float vs[4] = {f.x, f.y, f.z, f.w};
    u16 hh[4], mm[4], ll[4];
#pragma unroll
    for (int j = 0; j < 4; ++j) {
      float v = vs[j];
      u16 a = f2bf_rne(v); float fa = bf2f(a);
      u16 b = f2bf_rne(v - fa); float fb = bf2f(b);
      u16 c = f2bf_rne(v - fa - fb);
      hh[j] = a; mm[j] = b; ll[j] = c;
    }
    reinterpret_cast<ushort4*>(h)[i] = make_ushort4(hh[0], hh[1], hh[2], hh[3]);
    reinterpret_cast<ushort4*>(m)[i] = make_ushort4(mm[0], mm[1], mm[2], mm[3]);
    reinterpret_cast<ushort4*>(l)[i] = make_ushort4(ll[0], ll[1], ll[2], ll[3]);
  }
}

// ---------- transpose W_dec [1024][16384] -> WdT bf16 [16384][1024] ----------
__global__ __launch_bounds__(256)
void transpose_kernel(const float* __restrict__ Wd, u16* __restrict__ WdT) {
  __shared__ float tile[32][33];
  const int h0 = blockIdx.x * 32;
  const int o0 = blockIdx.y * 32;
  const int lx = threadIdx.x & 31;
  const int ly = threadIdx.x >> 5;  // 0..7
#pragma unroll
  for (int r = 0; r < 32; r += 8)
    tile[ly + r][lx] = Wd[(size_t)(o0 + ly + r) * HID_DIM + h0 + lx];
  __syncthreads();
#pragma unroll
  for (int r = 0; r < 32; r += 8)
    WdT[(size_t)(h0 + ly + r) * IN_DIM + o0 + lx] = f2bf_rne(tile[lx][ly + r]);
}

// ---------- GEMM: z = x @ W_enc^T via 6-term bf16 split MFMA ----------
// Per-output MFMA accumulation chain is BIT-IDENTICAL to rounds 1-3
// (same k0 order, same 6-term order, same fragment contents). Only the
// schedule changed: frags are register-resident before the MFMA phase, so
// k+1 staging overwrites the SAME LDS buffer concurrently with the MFMAs
// (single-buffer software pipeline; vmcnt drain hides under compute).
__global__ __launch_bounds__(256, 2)
void gemm6_kernel(const u16* __restrict__ xh, const u16* __restrict__ xm, const u16* __restrict__ xl,
                  const u16* __restrict__ wh, const u16* __restrict__ wm, const u16* __restrict__ wl,
                  float* __restrict__ z) {
  __shared__ u16 sA[3][128 * 32];
  __shared__ u16 sB[3][128 * 32];
  const int tid = threadIdx.x;
  const int lane = tid & 63;
  const int wave = tid >> 6;
  const int wr = (wave >> 1) * 64;
  const int wc = (wave & 1) * 64;

  const int bid = blockIdx.y * gridDim.x + blockIdx.x;      // 0..8191
  const int swz = (bid & 7) * 1024 + (bid >> 3);            // bijective
  const int mg = swz >> 10;                                 // 0..7
  const int within = swz & 1023;
  const int n_idx = within >> 3;                            // 0..127
  const int m_idx = (within & 7) + mg * 8;                  // 0..63
  const int m0 = m_idx * 128;
  const int n0 = n_idx * 128;

  const int srow = tid >> 2;
  const int scol = (((tid & 3) ^ ((srow >> 1) & 3)) * 8);

  const u16* gA[3] = {xh, xm, xl};
  const u16* gB[3] = {wh, wm, wl};

  const size_t aoff = (size_t)(m0 + srow) * IN_DIM + scol;
  const size_t boff = (size_t)(n0 + srow) * IN_DIM + scol;

  f32x4 acc[4][4] = {};

  const int rsel = lane & 15;
  const int ksel = (lane >> 4) * 8;

  // prologue: stage k0 = 0
#pragma unroll
  for (int s = 0; s < 3; ++s) {
    gload16(gA[s] + aoff,               &sA[s][tid * 8]);
    gload16(gA[s] + aoff + 64 * IN_DIM, &sA[s][2048 + tid * 8]);
    gload16(gB[s] + boff,               &sB[s][tid * 8]);
    gload16(gB[s] + boff + 64 * IN_DIM, &sB[s][2048 + tid * 8]);
  }
  __syncthreads();  // drains vmcnt(0): tile 0 resident

  for (int k0 = 0; k0 < IN_DIM; k0 += 32) {
    // 1) LDS -> registers: ALL fragments for step k0
    bf16x8 a[3][4], b[3][4];
#pragma unroll
    for (int t = 0; t < 4; ++t) {
      const int ra = wr + t * 16 + rsel;
      const int rb = wc + t * 16 + rsel;
      const int ka = ksel ^ (((ra >> 1) & 3) * 8);
      const int kb = ksel ^ (((rb >> 1) & 3) * 8);
#pragma unroll
      for (int s = 0; s < 3; ++s) {
        a[s][t] = *reinterpret_cast<const bf16x8*>(&sA[s][ra * 32 + ka]);
        b[s][t] = *reinterpret_cast<const bf16x8*>(&sB[s][rb * 32 + kb]);
      }
    }
    // 2) all waves done reading LDS (implicit lgkmcnt(0); no vmem outstanding)
    __syncthreads();
    // 3) stage k0+32 into the SAME buffer; loads fly during the MFMA phase
    if (k0 + 32 < IN_DIM) {
      const size_t ao = aoff + k0 + 32;
      const size_t bo = boff + k0 + 32;
#pragma unroll
      for (int s = 0; s < 3; ++s) {
        gload16(gA[s] + ao,               &sA[s][tid * 8]);
        gload16(gA[s] + ao + 64 * IN_DIM, &sA[s][2048 + tid * 8]);
        gload16(gB[s] + bo,               &sB[s][tid * 8]);
        gload16(gB[s] + bo + 64 * IN_DIM, &sB[s][2048 + tid * 8]);
      }
    }
    __builtin_amdgcn_sched_barrier(0);  // pin staging issue before the MFMAs
    // 4) MFMA phase (register-only) — exact same per-acc chain order as before
    __builtin_amdgcn_s_setprio(1);
#pragma unroll
    for (int mt = 0; mt < 4; ++mt)
#pragma unroll
      for (int nt = 0; nt < 4; ++nt) {
        f32x4 c = acc[mt][nt];
        c = __builtin_amdgcn_mfma_f32_16x16x32_bf16(a[0][mt], b[0][nt], c, 0, 0, 0); // hh
        c = __builtin_amdgcn_mfma_f32_16x16x32_bf16(a[0][mt], b[1][nt], c, 0, 0, 0); // hm
        c = __builtin_amdgcn_mfma_f32_16x16x32_bf16(a[1][mt], b[0][nt], c, 0, 0, 0); // mh
        c = __builtin_amdgcn_mfma_f32_16x16x32_bf16(a[0][mt], b[2][nt], c, 0, 0, 0); // hl
        c = __builtin_amdgcn_mfma_f32_16x16x32_bf16(a[1][mt], b[1][nt], c, 0, 0, 0); // mm
        c = __builtin_amdgcn_mfma_f32_16x16x32_bf16(a[2][mt], b[0][nt], c, 0, 0, 0); // lh
        acc[mt][nt] = c;
      }
    __builtin_amdgcn_s_setprio(0);
    // 5) vmcnt(0)+barrier: k0+32 staged (drain hidden under the MFMA stretch)
    __syncthreads();
  }

  const int col = lane & 15;
  const int r0 = (lane >> 4) * 4;
#pragma unroll
  for (int mt = 0; mt < 4; ++mt)
#pragma unroll
    for (int nt = 0; nt < 4; ++nt)
#pragma unroll
      for (int j = 0; j < 4; ++j) {
        const int rr = m0 + wr + mt * 16 + r0 + j;
        const int cc = n0 + wc + nt * 16 + col;
        z[(size_t)rr * HID_DIM + cc] = acc[mt][nt][j];
      }
}

// ---------- fused exact top-50 + sparsify + decode ----------
__global__ __launch_bounds__(TKT)
void topk_decode_kernel(float* __restrict__ z, const u16* __restrict__ WdT,
                        float* __restrict__ recon) {
  __shared__ float sv[HID_DIM];        // 64 KiB
  __shared__ float cval[CAND_CAP];     // 4 KiB
  __shared__ int   cidx[CAND_CAP];     // 4 KiB
  __shared__ float sredv[TKT / 64];
  __shared__ int   sredi[TKT / 64];
  __shared__ unsigned scnt;
  __shared__ float sthr, ssig;

  const int tid = threadIdx.x;
  const int lane = tid & 63;
  const int wv = tid >> 6;
  const size_t row = blockIdx.x;
  float* zrow = z + row * HID_DIM;

  // load row + sum of squares
  float ss = 0.f;
  for (int i = tid; i < HID_DIM / 4; i += TKT) {
    float4 v = reinterpret_cast<const float4*>(zrow)[i];
    reinterpret_cast<float4*>(sv)[i] = v;
    ss = fmaf(v.x, v.x, ss); ss = fmaf(v.y, v.y, ss);
    ss = fmaf(v.z, v.z, ss); ss = fmaf(v.w, v.w, ss);
  }
#pragma unroll
  for (int off = 32; off > 0; off >>= 1) ss += __shfl_down(ss, off);
  if (lane == 0) sredv[wv] = ss;
  __syncthreads();
  if (tid == 0) {
    float t = 0.f;
#pragma unroll
    for (int w = 0; w < TKT / 64; ++w) t += sredv[w];
    float sig = sqrtf(t / (float)HID_DIM);
    ssig = sig;
    sthr = 2.2f * sig;
  }
  __syncthreads();

  // candidate collection with threshold retry
  int cnt = 0;
  bool ok = false;
  for (int att = 0; att < 4; ++att) {
    if (tid == 0) scnt = 0;
    __syncthreads();
    const float th = sthr;
    for (int i = tid; i < HID_DIM; i += TKT) {
      float v = sv[i];
      if (v > th) {
        unsigned p = atomicAdd(&scnt, 1u);
        if (p < CAND_CAP) { cval[p] = v; cidx[p] = i; }
      }
    }
    __syncthreads();
    cnt = (int)scnt;
    if (cnt >= TOPK && cnt <= CAND_CAP) { ok = true; break; }
    if (tid == 0) sthr = (cnt < TOPK) ? (sthr - 0.7f * ssig) : (sthr + 0.7f * ssig);
    __syncthreads();
  }

  if (!ok) {
    // exact fallback: 50x block argmax
    for (int r = 0; r < TOPK; ++r) {
      float bv = ninf(); int bi = 0x7FFFFFFF;
      for (int i = tid; i < HID_DIM; i += TKT) {
        float v = sv[i];
        if (v > bv || (v == bv && i < bi)) { bv = v; bi = i; }
      }
#pragma unroll
      for (int off = 32; off > 0; off >>= 1) {
        float ov = __shfl_down(bv, off); int oi = __shfl_down(bi, off);
        if (ov > bv || (ov == bv && oi < bi)) { bv = ov; bi = oi; }
      }
      if (lane == 0) { sredv[wv] = bv; sredi[wv] = bi; }
      __syncthreads();
      if (tid == 0) {
        float Bv = ninf(); int Bi = 0x7FFFFFFF;
#pragma unroll
        for (int w = 0; w < TKT / 64; ++w) {
          if (sredv[w] > Bv || (sredv[w] == Bv && sredi[w] < Bi)) { Bv = sredv[w]; Bi = sredi[w]; }
        }
        cval[r] = Bv; cidx[r] = Bi; sv[Bi] = ninf();
      }
      __syncthreads();
    }
    if (tid < TOPK) sv[cidx[tid]] = cval[tid];
    if (tid == 0) scnt = TOPK;
    __syncthreads();
    cnt = TOPK;
  }

  // pad to pow2 and bitonic sort by (value desc, index asc)
  int P2 = 64;
  while (P2 < cnt) P2 <<= 1;
  for (int i = cnt + tid; i < P2; i += TKT) { cval[i] = ninf(); cidx[i] = 0x7FFFFFFF; }
  __syncthreads();
  for (int k = 2; k <= P2; k <<= 1) {
    for (int j = k >> 1; j > 0; j >>= 1) {
      for (int i = tid; i < P2; i += TKT) {
        const int l = i ^ j;
        if (l > i) {
          float va = cval[i], vb = cval[l];
          int ia = cidx[i], ib = cidx[l];
          const bool aGreater = (va > vb) || (va == vb && ia < ib);
          const bool up = ((i & k) == 0);
          if (up ? !aGreater : aGreater) {
            cval[i] = vb; cval[l] = va;
            cidx[i] = ib; cidx[l] = ia;
          }
        }
      }
      __syncthreads();
    }
  }

  const float T = cval[TOPK - 1];
  const int lastTie = cidx[TOPK - 1];

  // sparse z write: keep v>T, plus v==T with index <= lastTie
  for (int i = tid; i < HID_DIM; i += TKT) {
    float v = sv[i];
    zrow[i] = (v > T || (v == T && i <= lastTie)) ? v : 0.0f;
  }

  // fused decode: recon[row] = sum_j cval[j] * WdT[cidx[j]][:]
  float a0 = 0.f, a1 = 0.f;
  for (int j = 0; j < TOPK; ++j) {
    const float v = cval[j];
    const unsigned w2 = reinterpret_cast<const unsigned*>(WdT + (size_t)cidx[j] * IN_DIM)[tid];
    a0 = fmaf(v, __uint_as_float(w2 << 16), a0);
    a1 = fmaf(v, __uint_as_float(w2 & 0xFFFF0000u), a1);
  }
  reinterpret_cast<float2*>(recon + row * IN_DIM)[tid] = make_float2(a0, a1);
}

// ---------- launch ----------
extern "C" void kernel_launch(void* const* d_in, const int* in_sizes, int n_in,
                              void* d_out, int out_size, void* d_ws, size_t ws_size,
                              hipStream_t stream) {
  const float* x  = (const float*)d_in[0];
  const float* We = (const float*)d_in[1];
  const float* Wd = (const float*)d_in[2];
  float* recon = (float*)d_out;
  float* z = recon + (size_t)B_ROWS * IN_DIM;   // outputs concatenated: recon, z

  char* ws = (char*)d_ws;
  const size_t MB = 1024ull * 1024ull;
  u16* xh = (u16*)(ws + 0 * MB);     // 16 MiB each (8192x1024 bf16)
  u16* xm = (u16*)(ws + 16 * MB);
  u16* xl = (u16*)(ws + 32 * MB);
  u16* wh = (u16*)(ws + 48 * MB);    // 32 MiB each (16384x1024 bf16)
  u16* wmm = (u16*)(ws + 80 * MB);
  u16* wl = (u16*)(ws + 112 * MB);
  u16* WdT = (u16*)(ws + 144 * MB);  // 32 MiB (bf16)

  split3_kernel<<<2048, 256, 0, stream>>>(x, xh, xm, xl, B_ROWS * IN_DIM / 4);
  split3_kernel<<<2048, 256, 0, stream>>>(We, wh, wmm, wl, HID_DIM * IN_DIM / 4);
  transpose_kernel<<<dim3(HID_DIM / 32, IN_DIM / 32), 256, 0, stream>>>(Wd, WdT);
  gemm6_kernel<<<dim3(HID_DIM / 128, B_ROWS / 128), 256, 0, stream>>>(xh, xm, xl, wh, wmm, wl, z);
  topk_decode_kernel<<<B_ROWS, TKT, 0, stream>>>(z, WdT, recon);
}

// Round 5
// 1634.098 us; speedup vs baseline: 1.0150x; 1.0150x over previous
//
#include <hip/hip_runtime.h>
#include <cstdint>
#include <cstddef>

#define TOPK 50
#define B_ROWS 8192
#define IN_DIM 1024
#define HID_DIM 16384
#define TKT 512   // topk threads
#define CAND_CAP 1024

typedef unsigned short u16;
typedef __attribute__((ext_vector_type(8))) short bf16x8;
typedef __attribute__((ext_vector_type(4))) float f32x4;

// ---------- helpers ----------
__device__ inline u16 f2bf_rne(float f) {
  unsigned u = __float_as_uint(f);
  unsigned r = 0x7FFFu + ((u >> 16) & 1u);
  return (u16)((u + r) >> 16);
}
__device__ inline float bf2f(u16 h) { return __uint_as_float(((unsigned)h) << 16); }
__device__ inline float ninf() { return __uint_as_float(0xFF800000u); }

__device__ inline void gload16(const void* g, void* l) {
  __builtin_amdgcn_global_load_lds(
      (const __attribute__((address_space(1))) void*)g,
      (__attribute__((address_space(3))) void*)l, 16, 0, 0);
}

// ---------- split f32 -> bf16 h/m/l ----------
__global__ __launch_bounds__(256)
void split3_kernel(const float* __restrict__ in, u16* __restrict__ h,
                   u16* __restrict__ m, u16* __restrict__ l, int n4) {
  int i = blockIdx.x * 256 + threadIdx.x;
  const int stride = gridDim.x * 256;
  for (; i < n4; i += stride) {
    const float4 f = reinterpret_cast<const float4*>(in)[i];
    float vs[4] = {f.x, f.y, f.z, f.w};
    u16 hh[4], mm[4], ll[4];
#pragma unroll
    for (int j = 0; j < 4; ++j) {
      float v = vs[j];
      u16 a = f2bf_rne(v); float fa = bf2f(a);
      u16 b = f2bf_rne(v - fa); float fb = bf2f(b);
      u16 c = f2bf_rne(v - fa - fb);
      hh[j] = a; mm[j] = b; ll[j] = c;
    }
    reinterpret_cast<ushort4*>(h)[i] = make_ushort4(hh[0], hh[1], hh[2], hh[3]);
    reinterpret_cast<ushort4*>(m)[i] = make_ushort4(mm[0], mm[1], mm[2], mm[3]);
    reinterpret_cast<ushort4*>(l)[i] = make_ushort4(ll[0], ll[1], ll[2], ll[3]);
  }
}

// ---------- transpose W_dec [1024][16384] -> WdT bf16 [16384][1024] ----------
__global__ __launch_bounds__(256)
void transpose_kernel(const float* __restrict__ Wd, u16* __restrict__ WdT) {
  __shared__ float tile[32][33];
  const int h0 = blockIdx.x * 32;
  const int o0 = blockIdx.y * 32;
  const int lx = threadIdx.x & 31;
  const int ly = threadIdx.x >> 5;  // 0..7
#pragma unroll
  for (int r = 0; r < 32; r += 8)
    tile[ly + r][lx] = Wd[(size_t)(o0 + ly + r) * HID_DIM + h0 + lx];
  __syncthreads();
#pragma unroll
  for (int r = 0; r < 32; r += 8)
    WdT[(size_t)(h0 + ly + r) * IN_DIM + o0 + lx] = f2bf_rne(tile[lx][ly + r]);
}

// ---------- GEMM: z = x @ W_enc^T via 6-term bf16 split MFMA ----------
// Per-output MFMA accumulation chain BIT-IDENTICAL to rounds 1-4 (same
// 16x16x32 shape, same ascending k0, same hh,hm,mh,hl,mm,lh order, same
// fragment values). Geometry changed to cut LDS-read bytes per FLOP:
// block tile 128x256, 4 waves, wave tile 64x128 (acc 4x8), B fragments
// streamed 3-at-a-time inside the nt loop.
__global__ __launch_bounds__(256, 2)
void gemm6_kernel(const u16* __restrict__ xh, const u16* __restrict__ xm, const u16* __restrict__ xl,
                  const u16* __restrict__ wh, const u16* __restrict__ wm, const u16* __restrict__ wl,
                  float* __restrict__ z) {
  __shared__ u16 sA[3][128 * 32];   // 24 KiB
  __shared__ u16 sB[3][256 * 32];   // 48 KiB
  const int tid = threadIdx.x;
  const int lane = tid & 63;
  const int wave = tid >> 6;
  const int wr = (wave >> 1) * 64;    // 0,64
  const int wc = (wave & 1) * 128;    // 0,128

  // XCD swizzle: 4096 blocks, 8 XCDs; XCD c owns m-tiles [8c,8c+8), n-major
  // within (8 consecutive blocks share one B panel; A panel 6MB XCD-resident).
  const int bid = blockIdx.y * gridDim.x + blockIdx.x;  // 0..4095
  const int xcd = bid & 7;
  const int within = bid >> 3;          // 0..511
  const int n_idx = within >> 3;        // 0..63
  const int m_idx = xcd * 8 + (within & 7);  // 0..63
  const int m0 = m_idx * 128;
  const int n0 = n_idx * 256;

  const int srow = tid >> 2;                               // 0..63
  const int scol = (((tid & 3) ^ ((srow >> 1) & 3)) * 8);  // swizzled k-slot

  const u16* gA[3] = {xh, xm, xl};
  const u16* gB[3] = {wh, wm, wl};

  const size_t aoff = (size_t)(m0 + srow) * IN_DIM + scol;
  const size_t boff = (size_t)(n0 + srow) * IN_DIM + scol;

  f32x4 acc[4][8] = {};

  const int rsel = lane & 15;
  const int ksel = (lane >> 4) * 8;

  // prologue: stage k0 = 0 (A: 2 row-groups, B: 4 row-groups, x3 splits)
#pragma unroll
  for (int s = 0; s < 3; ++s) {
    gload16(gA[s] + aoff,                &sA[s][tid * 8]);
    gload16(gA[s] + aoff + 64 * IN_DIM,  &sA[s][2048 + tid * 8]);
    gload16(gB[s] + boff,                &sB[s][tid * 8]);
    gload16(gB[s] + boff + 64 * IN_DIM,  &sB[s][2048 + tid * 8]);
    gload16(gB[s] + boff + 128 * IN_DIM, &sB[s][4096 + tid * 8]);
    gload16(gB[s] + boff + 192 * IN_DIM, &sB[s][6144 + tid * 8]);
  }
  __syncthreads();

  for (int k0 = 0; k0 < IN_DIM; k0 += 32) {
    // A fragments resident for the whole step
    bf16x8 a0[4], a1[4], a2[4];
#pragma unroll
    for (int t = 0; t < 4; ++t) {
      const int ra = wr + t * 16 + rsel;
      const int ka = ksel ^ (((ra >> 1) & 3) * 8);
      a0[t] = *reinterpret_cast<const bf16x8*>(&sA[0][ra * 32 + ka]);
      a1[t] = *reinterpret_cast<const bf16x8*>(&sA[1][ra * 32 + ka]);
      a2[t] = *reinterpret_cast<const bf16x8*>(&sA[2][ra * 32 + ka]);
    }
    __builtin_amdgcn_s_setprio(1);
#pragma unroll
    for (int nt = 0; nt < 8; ++nt) {
      const int rb = wc + nt * 16 + rsel;
      const int kb = ksel ^ (((rb >> 1) & 3) * 8);
      const bf16x8 b0 = *reinterpret_cast<const bf16x8*>(&sB[0][rb * 32 + kb]);
      const bf16x8 b1 = *reinterpret_cast<const bf16x8*>(&sB[1][rb * 32 + kb]);
      const bf16x8 b2 = *reinterpret_cast<const bf16x8*>(&sB[2][rb * 32 + kb]);
#pragma unroll
      for (int mt = 0; mt < 4; ++mt) {
        f32x4 c = acc[mt][nt];
        c = __builtin_amdgcn_mfma_f32_16x16x32_bf16(a0[mt], b0, c, 0, 0, 0); // hh
        c = __builtin_amdgcn_mfma_f32_16x16x32_bf16(a0[mt], b1, c, 0, 0, 0); // hm
        c = __builtin_amdgcn_mfma_f32_16x16x32_bf16(a1[mt], b0, c, 0, 0, 0); // mh
        c = __builtin_amdgcn_mfma_f32_16x16x32_bf16(a0[mt], b2, c, 0, 0, 0); // hl
        c = __builtin_amdgcn_mfma_f32_16x16x32_bf16(a1[mt], b1, c, 0, 0, 0); // mm
        c = __builtin_amdgcn_mfma_f32_16x16x32_bf16(a2[mt], b0, c, 0, 0, 0); // lh
        acc[mt][nt] = c;
      }
    }
    __builtin_amdgcn_s_setprio(0);
    __syncthreads();  // all waves done reading this K-tile
    if (k0 + 32 < IN_DIM) {
      const size_t ao = aoff + k0 + 32;
      const size_t bo = boff + k0 + 32;
#pragma unroll
      for (int s = 0; s < 3; ++s) {
        gload16(gA[s] + ao,                &sA[s][tid * 8]);
        gload16(gA[s] + ao + 64 * IN_DIM,  &sA[s][2048 + tid * 8]);
        gload16(gB[s] + bo,                &sB[s][tid * 8]);
        gload16(gB[s] + bo + 64 * IN_DIM,  &sB[s][2048 + tid * 8]);
        gload16(gB[s] + bo + 128 * IN_DIM, &sB[s][4096 + tid * 8]);
        gload16(gB[s] + bo + 192 * IN_DIM, &sB[s][6144 + tid * 8]);
      }
    }
    __syncthreads();  // vmcnt drain; cross-block overlap hides the latency
  }

  // epilogue: C/D layout col=lane&15, row=(lane>>4)*4+j
  const int col = lane & 15;
  const int r0 = (lane >> 4) * 4;
#pragma unroll
  for (int mt = 0; mt < 4; ++mt)
#pragma unroll
    for (int nt = 0; nt < 8; ++nt)
#pragma unroll
      for (int j = 0; j < 4; ++j) {
        const int rr = m0 + wr + mt * 16 + r0 + j;
        const int cc = n0 + wc + nt * 16 + col;
        z[(size_t)rr * HID_DIM + cc] = acc[mt][nt][j];
      }
}

// ---------- fused exact top-50 + sparsify + decode ----------
__global__ __launch_bounds__(TKT)
void topk_decode_kernel(float* __restrict__ z, const u16* __restrict__ WdT,
                        float* __restrict__ recon) {
  __shared__ float sv[HID_DIM];        // 64 KiB
  __shared__ float cval[CAND_CAP];     // 4 KiB
  __shared__ int   cidx[CAND_CAP];     // 4 KiB
  __shared__ float sredv[TKT / 64];
  __shared__ int   sredi[TKT / 64];
  __shared__ unsigned scnt;
  __shared__ float sthr, ssig;

  const int tid = threadIdx.x;
  const int lane = tid & 63;
  const int wv = tid >> 6;
  const size_t row = blockIdx.x;
  float* zrow = z + row * HID_DIM;

  // load row + sum of squares
  float ss = 0.f;
  for (int i = tid; i < HID_DIM / 4; i += TKT) {
    float4 v = reinterpret_cast<const float4*>(zrow)[i];
    reinterpret_cast<float4*>(sv)[i] = v;
    ss = fmaf(v.x, v.x, ss); ss = fmaf(v.y, v.y, ss);
    ss = fmaf(v.z, v.z, ss); ss = fmaf(v.w, v.w, ss);
  }
#pragma unroll
  for (int off = 32; off > 0; off >>= 1) ss += __shfl_down(ss, off);
  if (lane == 0) sredv[wv] = ss;
  __syncthreads();
  if (tid == 0) {
    float t = 0.f;
#pragma unroll
    for (int w = 0; w < TKT / 64; ++w) t += sredv[w];
    float sig = sqrtf(t / (float)HID_DIM);
    ssig = sig;
    sthr = 2.2f * sig;
  }
  __syncthreads();

  // candidate collection with threshold retry
  int cnt = 0;
  bool ok = false;
  for (int att = 0; att < 4; ++att) {
    if (tid == 0) scnt = 0;
    __syncthreads();
    const float th = sthr;
    for (int i = tid; i < HID_DIM; i += TKT) {
      float v = sv[i];
      if (v > th) {
        unsigned p = atomicAdd(&scnt, 1u);
        if (p < CAND_CAP) { cval[p] = v; cidx[p] = i; }
      }
    }
    __syncthreads();
    cnt = (int)scnt;
    if (cnt >= TOPK && cnt <= CAND_CAP) { ok = true; break; }
    if (tid == 0) sthr = (cnt < TOPK) ? (sthr - 0.7f * ssig) : (sthr + 0.7f * ssig);
    __syncthreads();
  }

  if (!ok) {
    // exact fallback: 50x block argmax
    for (int r = 0; r < TOPK; ++r) {
      float bv = ninf(); int bi = 0x7FFFFFFF;
      for (int i = tid; i < HID_DIM; i += TKT) {
        float v = sv[i];
        if (v > bv || (v == bv && i < bi)) { bv = v; bi = i; }
      }
#pragma unroll
      for (int off = 32; off > 0; off >>= 1) {
        float ov = __shfl_down(bv, off); int oi = __shfl_down(bi, off);
        if (ov > bv || (ov == bv && oi < bi)) { bv = ov; bi = oi; }
      }
      if (lane == 0) { sredv[wv] = bv; sredi[wv] = bi; }
      __syncthreads();
      if (tid == 0) {
        float Bv = ninf(); int Bi = 0x7FFFFFFF;
#pragma unroll
        for (int w = 0; w < TKT / 64; ++w) {
          if (sredv[w] > Bv || (sredv[w] == Bv && sredi[w] < Bi)) { Bv = sredv[w]; Bi = sredi[w]; }
        }
        cval[r] = Bv; cidx[r] = Bi; sv[Bi] = ninf();
      }
      __syncthreads();
    }
    if (tid < TOPK) sv[cidx[tid]] = cval[tid];
    if (tid == 0) scnt = TOPK;
    __syncthreads();
    cnt = TOPK;
  }

  // pad to pow2 and bitonic sort by (value desc, index asc)
  int P2 = 64;
  while (P2 < cnt) P2 <<= 1;
  for (int i = cnt + tid; i < P2; i += TKT) { cval[i] = ninf(); cidx[i] = 0x7FFFFFFF; }
  __syncthreads();
  for (int k = 2; k <= P2; k <<= 1) {
    for (int j = k >> 1; j > 0; j >>= 1) {
      for (int i = tid; i < P2; i += TKT) {
        const int l = i ^ j;
        if (l > i) {
          float va = cval[i], vb = cval[l];
          int ia = cidx[i], ib = cidx[l];
          const bool aGreater = (va > vb) || (va == vb && ia < ib);
          const bool up = ((i & k) == 0);
          if (up ? !aGreater : aGreater) {
            cval[i] = vb; cval[l] = va;
            cidx[i] = ib; cidx[l] = ia;
          }
        }
      }
      __syncthreads();
    }
  }

  const float T = cval[TOPK - 1];
  const int lastTie = cidx[TOPK - 1];

  // sparse z write: keep v>T, plus v==T with index <= lastTie
  for (int i = tid; i < HID_DIM; i += TKT) {
    float v = sv[i];
    zrow[i] = (v > T || (v == T && i <= lastTie)) ? v : 0.0f;
  }

  // fused decode: recon[row] = sum_j cval[j] * WdT[cidx[j]][:]
  float a0 = 0.f, a1 = 0.f;
  for (int j = 0; j < TOPK; ++j) {
    const float v = cval[j];
    const unsigned w2 = reinterpret_cast<const unsigned*>(WdT + (size_t)cidx[j] * IN_DIM)[tid];
    a0 = fmaf(v, __uint_as_float(w2 << 16), a0);
    a1 = fmaf(v, __uint_as_float(w2 & 0xFFFF0000u), a1);
  }
  reinterpret_cast<float2*>(recon + row * IN_DIM)[tid] = make_float2(a0, a1);
}

// ---------- launch ----------
extern "C" void kernel_launch(void* const* d_in, const int* in_sizes, int n_in,
                              void* d_out, int out_size, void* d_ws, size_t ws_size,
                              hipStream_t stream) {
  const float* x  = (const float*)d_in[0];
  const float* We = (const float*)d_in[1];
  const float* Wd = (const float*)d_in[2];
  float* recon = (float*)d_out;
  float* z = recon + (size_t)B_ROWS * IN_DIM;   // outputs concatenated: recon, z

  char* ws = (char*)d_ws;
  const size_t MB = 1024ull * 1024ull;
  u16* xh = (u16*)(ws + 0 * MB);     // 16 MiB each (8192x1024 bf16)
  u16* xm = (u16*)(ws + 16 * MB);
  u16* xl = (u16*)(ws + 32 * MB);
  u16* wh = (u16*)(ws + 48 * MB);    // 32 MiB each (16384x1024 bf16)
  u16* wmm = (u16*)(ws + 80 * MB);
  u16* wl = (u16*)(ws + 112 * MB);
  u16* WdT = (u16*)(ws + 144 * MB);  // 32 MiB (bf16)

  split3_kernel<<<2048, 256, 0, stream>>>(x, xh, xm, xl, B_ROWS * IN_DIM / 4);
  split3_kernel<<<2048, 256, 0, stream>>>(We, wh, wmm, wl, HID_DIM * IN_DIM / 4);
  transpose_kernel<<<dim3(HID_DIM / 32, IN_DIM / 32), 256, 0, stream>>>(Wd, WdT);
  gemm6_kernel<<<dim3(HID_DIM / 256, B_ROWS / 128), 256, 0, stream>>>(xh, xm, xl, wh, wmm, wl, z);
  topk_decode_kernel<<<B_ROWS, TKT, 0, stream>>>(z, WdT, recon);
}